// Round 1
// baseline (497.378 us; speedup 1.0000x reference)
//
#include <hip/hip_runtime.h>

// ---------------------------------------------------------------------------
// EncoderLayer: x -> MHA(entmax1.5) -> +LN -> FFN(mish) -> +LN
// B=8 S=1024 D=512 H=8 hd=64 F=2048.  bf16 MFMA GEMMs, fp32 accum/epilogues.
// ---------------------------------------------------------------------------

typedef float f32x4 __attribute__((ext_vector_type(4)));
typedef __bf16 b8 __attribute__((ext_vector_type(8)));

#define DEV static __device__ __forceinline__

DEV unsigned short f2bf(float f) {
  unsigned u = __float_as_uint(f);
  u += 0x7fffu + ((u >> 16) & 1u);   // RNE
  return (unsigned short)(u >> 16);
}
DEV float bf2f(unsigned short b) { return __uint_as_float(((unsigned)b) << 16); }

DEV float mishf(float x) {
  // x * tanh(softplus(x)) == x * ((1+e^x)^2 - 1)/((1+e^x)^2 + 1)
  if (x > 20.f) return x;
  float e = __expf(x);
  float u = 1.f + e;
  u *= u;
  return x * ((u - 1.f) / (u + 1.f));
}

DEV void async16(const void* g, void* l) {
  __builtin_amdgcn_global_load_lds(
      (const __attribute__((address_space(1))) unsigned int*)g,
      (__attribute__((address_space(3))) unsigned int*)l, 16, 0, 0);
}

// ---------------------------------------------------------------------------
// Generic MFMA GEMM:  C[M,N] = alpha * A[M,K] * Bt[N,K]^T (+bias) (+mish)
// A, Bt bf16 row-major (lda/ldb leading strides). Batched via blockIdx.z with
// composite offsets off = (z/hdiv)*s1 + (z%hdiv)*s2 for A, B, C.
// Block: 256 threads = 4 waves; wave grid WM x WN, each wave does 64x64 via
// 4x4 of mfma_f32_16x16x32_bf16. BK=32 per step, global_load_lds staging,
// XOR-swizzled 16B slots so frag ds_read_b128 is 2-way-conflict (free).
// EPI: 0 none, 1 +bias, 2 +bias+mish.  OUTBF: bf16 vs fp32 output.
// ---------------------------------------------------------------------------
template <int WM, int WN, int EPI, bool OUTBF>
__global__ __launch_bounds__(256) void gemm_bt(
    const unsigned short* __restrict__ A, const unsigned short* __restrict__ Bt,
    const float* __restrict__ bias, void* __restrict__ Cp,
    int K, int lda, int ldb, int ldc,
    long sA1, long sA2, long sB1, long sB2, long sC1, long sC2,
    int hdiv, float alpha) {
  constexpr int BM = WM * 64, BN = WN * 64;
  __shared__ unsigned short smA[BM * 32];
  __shared__ unsigned short smB[BN * 32];

  const int tid = threadIdx.x;
  const int lane = tid & 63;
  const int z = blockIdx.z;
  const long zi = z / hdiv, zr = z % hdiv;
  const unsigned short* Ab = A + zi * sA1 + zr * sA2 + (long)blockIdx.x * BM * lda;
  const unsigned short* Bb = Bt + zi * sB1 + zr * sB2 + (long)blockIdx.y * BN * ldb;

  // staging descriptors: slot si holds row m=si>>2, slot s=si&3, containing
  // global k-group g = s ^ ((m>>1)&3)   (involution; breaks frag-read conflicts)
  int siA[WM];
  const unsigned short* gA[WM];
#pragma unroll
  for (int q = 0; q < WM; ++q) {
    int si = q * 256 + tid;
    int m = si >> 2, s = si & 3, g = s ^ ((m >> 1) & 3);
    siA[q] = si;
    gA[q] = Ab + (long)m * lda + g * 8;
  }
  int siB[WN];
  const unsigned short* gB[WN];
#pragma unroll
  for (int q = 0; q < WN; ++q) {
    int si = q * 256 + tid;
    int m = si >> 2, s = si & 3, g = s ^ ((m >> 1) & 3);
    siB[q] = si;
    gB[q] = Bb + (long)m * ldb + g * 8;
  }

  const int w = tid >> 6;
  const int wr = w / WN, wc = w % WN;
  const int fm = lane & 15, fg = lane >> 4;

  int aOff[4], bOff[4];
#pragma unroll
  for (int i = 0; i < 4; ++i) {
    int m = wr * 64 + i * 16 + fm;
    aOff[i] = (m * 4 + (fg ^ ((m >> 1) & 3))) * 8;
    int n = wc * 64 + i * 16 + fm;
    bOff[i] = (n * 4 + (fg ^ ((n >> 1) & 3))) * 8;
  }

  f32x4 acc[4][4];
#pragma unroll
  for (int i = 0; i < 4; ++i)
#pragma unroll
    for (int j = 0; j < 4; ++j) acc[i][j] = (f32x4){0.f, 0.f, 0.f, 0.f};

  for (int k0 = 0; k0 < K; k0 += 32) {
    __syncthreads();  // protect LDS from previous iteration's readers
#pragma unroll
    for (int q = 0; q < WM; ++q) async16(gA[q] + k0, (void*)&smA[siA[q] * 8]);
#pragma unroll
    for (int q = 0; q < WN; ++q) async16(gB[q] + k0, (void*)&smB[siB[q] * 8]);
    __syncthreads();  // implies vmcnt(0): staging complete

    b8 aF[4], bF[4];
#pragma unroll
    for (int i = 0; i < 4; ++i) aF[i] = *(const b8*)&smA[aOff[i]];
#pragma unroll
    for (int j = 0; j < 4; ++j) bF[j] = *(const b8*)&smB[bOff[j]];
#pragma unroll
    for (int i = 0; i < 4; ++i)
#pragma unroll
      for (int j = 0; j < 4; ++j)
        acc[i][j] = __builtin_amdgcn_mfma_f32_16x16x32_bf16(aF[i], bF[j], acc[i][j], 0, 0, 0);
  }

  // epilogue: C row = (lane>>4)*4 + reg, col = lane&15 (m89-verified layout)
  const long cbase = zi * sC1 + zr * sC2;
  const int row0 = blockIdx.x * BM + wr * 64 + fg * 4;
  const int col0 = blockIdx.y * BN + wc * 64 + fm;
#pragma unroll
  for (int i = 0; i < 4; ++i) {
#pragma unroll
    for (int j = 0; j < 4; ++j) {
      const int col = col0 + j * 16;
      float bv = (EPI >= 1) ? bias[col] : 0.f;
#pragma unroll
      for (int r = 0; r < 4; ++r) {
        const int row = row0 + i * 16 + r;
        float v = acc[i][j][r] * alpha + bv;
        if (EPI == 2) v = mishf(v);
        const long idx = cbase + (long)row * ldc + col;
        if constexpr (OUTBF)
          ((unsigned short*)Cp)[idx] = f2bf(v);
        else
          ((float*)Cp)[idx] = v;
      }
    }
  }
}

// ---------------------------------------------------------------------------
// fp32 -> bf16 cast (vectorized)
// ---------------------------------------------------------------------------
__global__ __launch_bounds__(256) void cast_f2b(const float* __restrict__ in,
                                                unsigned short* __restrict__ out, long n) {
  long i = ((long)blockIdx.x * 256 + threadIdx.x) * 4;
  if (i >= n) return;
  float4 v = *(const float4*)&in[i];
  unsigned lo = (unsigned)f2bf(v.x) | ((unsigned)f2bf(v.y) << 16);
  unsigned hi = (unsigned)f2bf(v.z) | ((unsigned)f2bf(v.w) << 16);
  uint2 p;
  p.x = lo;
  p.y = hi;
  *(uint2*)&out[i] = p;
}

// ---------------------------------------------------------------------------
// Transpose fp32[R,C] (ldi) -> bf16[C,R] (ldo), 32x32 LDS tiles (weights)
// ---------------------------------------------------------------------------
__global__ __launch_bounds__(256) void transpose_f2b(const float* __restrict__ in,
                                                     unsigned short* __restrict__ out,
                                                     int ldi, int ldo) {
  __shared__ float t[32][33];
  const int tx = threadIdx.x & 31, ty = threadIdx.x >> 5;
  const int r0 = blockIdx.y * 32, c0 = blockIdx.x * 32;
#pragma unroll
  for (int q = 0; q < 4; ++q) {
    int r = ty + q * 8;
    t[r][tx] = in[(long)(r0 + r) * ldi + c0 + tx];
  }
  __syncthreads();
#pragma unroll
  for (int q = 0; q < 4; ++q) {
    int r = ty + q * 8;
    out[(long)(c0 + r) * ldo + r0 + tx] = f2bf(t[tx][r]);
  }
}

// bf16 batched transpose (for V -> V^T per (b,h))
__global__ __launch_bounds__(256) void transpose_b2b(const unsigned short* __restrict__ in,
                                                     unsigned short* __restrict__ out,
                                                     int ldi, int ldo, long i1, long i2,
                                                     long o1, long o2, int hdiv) {
  __shared__ unsigned short t[32][33];
  const int z = blockIdx.z;
  in += (long)(z / hdiv) * i1 + (long)(z % hdiv) * i2;
  out += (long)(z / hdiv) * o1 + (long)(z % hdiv) * o2;
  const int tx = threadIdx.x & 31, ty = threadIdx.x >> 5;
  const int r0 = blockIdx.y * 32, c0 = blockIdx.x * 32;
#pragma unroll
  for (int q = 0; q < 4; ++q) {
    int r = ty + q * 8;
    t[r][tx] = in[(long)(r0 + r) * ldi + c0 + tx];
  }
  __syncthreads();
#pragma unroll
  for (int q = 0; q < 4; ++q) {
    int r = ty + q * 8;
    out[(long)(c0 + r) * ldo + r0 + tx] = t[tx][r];
  }
}

// ---------------------------------------------------------------------------
// entmax 1.5 over rows of 1024 (in-place on bf16 buffer). One wave per row.
// z already = scores/2 (folded into GEMM alpha). tau* solves sum (z-tau)_+^2=1
// and tau* >= z_max - 1, so only z > max-1 can be in support -> compact then
// Newton from below (monotone convergent: f convex decreasing).
// ---------------------------------------------------------------------------
__global__ __launch_bounds__(256) void entmax_rows(unsigned short* __restrict__ P) {
  __shared__ float ebuf[4][1024];
  __shared__ int ecnt[4];
  const int tid = threadIdx.x, lane = tid & 63, wv = tid >> 6;
  const long row = (long)blockIdx.x * 4 + wv;
  unsigned short* p = P + row * 1024;

  float zv[16];
  union {
    uint4 v;
    unsigned short u[8];
  } a, b;
  a.v = *(const uint4*)(p + lane * 16);
  b.v = *(const uint4*)(p + lane * 16 + 8);
#pragma unroll
  for (int i = 0; i < 8; ++i) {
    zv[i] = bf2f(a.u[i]);
    zv[8 + i] = bf2f(b.u[i]);
  }

  float m = zv[0];
#pragma unroll
  for (int i = 1; i < 16; ++i) m = fmaxf(m, zv[i]);
  for (int o = 32; o; o >>= 1) m = fmaxf(m, __shfl_xor(m, o));

  int cnt = 0;
#pragma unroll
  for (int i = 0; i < 16; ++i) {
    zv[i] -= m;
    if (zv[i] > -1.f) ++cnt;
  }

  if (lane == 0) ecnt[wv] = 0;
  __syncthreads();
  int pos = atomicAdd(&ecnt[wv], cnt);
#pragma unroll
  for (int i = 0; i < 16; ++i)
    if (zv[i] > -1.f) ebuf[wv][pos++] = zv[i];
  __syncthreads();

  const int n = ecnt[wv];
  const int nIter = (n + 63) >> 6;
  float tau = -1.f;
  for (int it = 0; it < 24; ++it) {
    float s1 = 0.f, s2 = 0.f;
    for (int t = 0; t < nIter; ++t) {
      int idx = (t << 6) + lane;
      if (idx < n) {
        float h = ebuf[wv][idx] - tau;
        if (h > 0.f) {
          s1 += h;
          s2 += h * h;
        }
      }
    }
    for (int o = 32; o; o >>= 1) {
      s1 += __shfl_xor(s1, o);
      s2 += __shfl_xor(s2, o);
    }
    if (s2 - 1.f < 1e-7f) break;  // converged (approach from below)
    tau += (s2 - 1.f) / (2.f * s1);
  }

#pragma unroll
  for (int i = 0; i < 8; ++i) {
    float h0 = zv[i] - tau;
    float h1 = zv[8 + i] - tau;
    a.u[i] = f2bf(h0 > 0.f ? h0 * h0 : 0.f);
    b.u[i] = f2bf(h1 > 0.f ? h1 * h1 : 0.f);
  }
  *(uint4*)(p + lane * 16) = a.v;
  *(uint4*)(p + lane * 16 + 8) = b.v;
}

// ---------------------------------------------------------------------------
// out = xin + LayerNorm(y)*g + be   (row length 512, 256 threads/row)
// optionally also writes bf16 copy of out.
// ---------------------------------------------------------------------------
template <bool WB>
__global__ __launch_bounds__(256) void ln_res(const float* __restrict__ xin,
                                              const float* __restrict__ y,
                                              const float* __restrict__ g,
                                              const float* __restrict__ be,
                                              float* __restrict__ xo,
                                              unsigned short* __restrict__ xob) {
  const int row = blockIdx.x, tid = threadIdx.x, lane = tid & 63, wv = tid >> 6;
  const long base = (long)row * 512 + tid * 2;
  float2 v = *(const float2*)&y[base];
  float s1 = v.x + v.y, s2 = v.x * v.x + v.y * v.y;
  for (int o = 32; o; o >>= 1) {
    s1 += __shfl_xor(s1, o);
    s2 += __shfl_xor(s2, o);
  }
  __shared__ float red[4][2];
  if (lane == 0) {
    red[wv][0] = s1;
    red[wv][1] = s2;
  }
  __syncthreads();
  s1 = red[0][0] + red[1][0] + red[2][0] + red[3][0];
  s2 = red[0][1] + red[1][1] + red[2][1] + red[3][1];
  const float mu = s1 * (1.f / 512.f);
  const float rstd = rsqrtf(s2 * (1.f / 512.f) - mu * mu + 1e-5f);
  const int c = tid * 2;
  float2 xv = *(const float2*)&xin[base];
  float o0 = xv.x + (v.x - mu) * rstd * g[c] + be[c];
  float o1 = xv.y + (v.y - mu) * rstd * g[c + 1] + be[c + 1];
  float2 ov;
  ov.x = o0;
  ov.y = o1;
  *(float2*)&xo[base] = ov;
  if constexpr (WB) {
    unsigned pk = (unsigned)f2bf(o0) | ((unsigned)f2bf(o1) << 16);
    *(unsigned*)&xob[base] = pk;
  }
}

// ---------------------------------------------------------------------------
extern "C" void kernel_launch(void* const* d_in, const int* in_sizes, int n_in,
                              void* d_out, int out_size, void* d_ws, size_t ws_size,
                              hipStream_t stream) {
  const int B = 8, S = 1024, D = 512, H = 8, F = 2048;
  const int BS = B * S;  // 8192 rows

  const float* x = (const float*)d_in[0];
  const float* Wq = (const float*)d_in[1];
  const float* bq = (const float*)d_in[2];
  const float* Wk = (const float*)d_in[3];
  const float* bk = (const float*)d_in[4];
  const float* Wv = (const float*)d_in[5];
  const float* bv = (const float*)d_in[6];
  const float* Wo = (const float*)d_in[7];
  const float* bo = (const float*)d_in[8];
  const float* g1 = (const float*)d_in[9];
  const float* be1 = (const float*)d_in[10];
  const float* W1 = (const float*)d_in[11];
  const float* b1 = (const float*)d_in[12];
  const float* W2 = (const float*)d_in[13];
  const float* b2 = (const float*)d_in[14];
  const float* g2 = (const float*)d_in[15];
  const float* be2 = (const float*)d_in[16];
  float* out = (float*)d_out;

  char* w = (char*)d_ws;
  size_t off = 0;
  auto alloc = [&](size_t bytes) -> void* {
    void* p = w + off;
    off += bytes;
    off = (off + 255) & ~(size_t)255;
    return p;
  };

  unsigned short* xb = (unsigned short*)alloc((size_t)BS * D * 2);
  unsigned short* Wqt = (unsigned short*)alloc((size_t)D * D * 2);
  unsigned short* Wkt = (unsigned short*)alloc((size_t)D * D * 2);
  unsigned short* Wvt = (unsigned short*)alloc((size_t)D * D * 2);
  unsigned short* Wot = (unsigned short*)alloc((size_t)D * D * 2);
  unsigned short* W1t = (unsigned short*)alloc((size_t)F * D * 2);
  unsigned short* W2t = (unsigned short*)alloc((size_t)D * F * 2);
  unsigned short* Qb = (unsigned short*)alloc((size_t)BS * D * 2);
  unsigned short* Kb = (unsigned short*)alloc((size_t)BS * D * 2);
  unsigned short* Vb = (unsigned short*)alloc((size_t)BS * D * 2);
  unsigned short* Vt = (unsigned short*)alloc((size_t)BS * D * 2);
  unsigned short* P = (unsigned short*)alloc((size_t)B * H * S * S * 2);  // 128 MiB
  float* yb = (float*)alloc((size_t)BS * D * 4);
  float* x1 = (float*)alloc((size_t)BS * D * 4);
  unsigned short* hb = (unsigned short*)alloc((size_t)BS * F * 2);
  unsigned short* attn = Qb;  // reuse (Qb dead after scores GEMM)
  unsigned short* x1b = xb;   // reuse (xb dead after QKV GEMMs)

  const long SD = (long)S * D;      // 524288
  const long SS = (long)S * S;      // 1048576
  const long HSS = (long)H * SS;    // per-b score stride
  const long HDS = (long)H * 64 * S;  // per-b Vt stride

  // 1) casts + weight transposes (bf16, N x K form)
  cast_f2b<<<(BS * D) / 1024, 256, 0, stream>>>(x, xb, (long)BS * D);
  transpose_f2b<<<dim3(16, 16, 1), 256, 0, stream>>>(Wq, Wqt, D, D);
  transpose_f2b<<<dim3(16, 16, 1), 256, 0, stream>>>(Wk, Wkt, D, D);
  transpose_f2b<<<dim3(16, 16, 1), 256, 0, stream>>>(Wv, Wvt, D, D);
  transpose_f2b<<<dim3(16, 16, 1), 256, 0, stream>>>(Wo, Wot, D, D);
  transpose_f2b<<<dim3(F / 32, D / 32, 1), 256, 0, stream>>>(W1, W1t, F, D);
  transpose_f2b<<<dim3(D / 32, F / 32, 1), 256, 0, stream>>>(W2, W2t, D, F);

  // 2) Q,K,V projections (bf16 out)
  gemm_bt<2, 2, 1, true><<<dim3(BS / 128, D / 128, 1), 256, 0, stream>>>(
      xb, Wqt, bq, Qb, D, D, D, D, 0, 0, 0, 0, 0, 0, 1, 1.f);
  gemm_bt<2, 2, 1, true><<<dim3(BS / 128, D / 128, 1), 256, 0, stream>>>(
      xb, Wkt, bk, Kb, D, D, D, D, 0, 0, 0, 0, 0, 0, 1, 1.f);
  gemm_bt<2, 2, 1, true><<<dim3(BS / 128, D / 128, 1), 256, 0, stream>>>(
      xb, Wvt, bv, Vb, D, D, D, D, 0, 0, 0, 0, 0, 0, 1, 1.f);

  // 3) V -> Vt[(b,h), d, s]
  transpose_b2b<<<dim3(2, 32, B * H), 256, 0, stream>>>(Vb, Vt, D, S, SD, 64, HDS,
                                                        (long)64 * S, H);

  // 4) scores z = Q K^T / 16  (the /8 attention scale * entmax /2), bf16
  gemm_bt<2, 2, 0, true><<<dim3(S / 128, S / 128, B * H), 256, 0, stream>>>(
      Qb, Kb, nullptr, P, 64, D, D, S, SD, 64, SD, 64, HSS, SS, H, 1.f / 16.f);

  // 5) entmax-1.5 per row, in place
  entmax_rows<<<(B * H * S) / 4, 256, 0, stream>>>(P);

  // 6) attn_out = P @ V   (256x64 tiles)
  gemm_bt<4, 1, 0, true><<<dim3(S / 256, 1, B * H), 256, 0, stream>>>(
      P, Vt, nullptr, attn, S, S, S, D, HSS, SS, HDS, (long)64 * S, SD, 64, H, 1.f);

  // 7) y = attn_out @ Wo + bo (fp32)
  gemm_bt<2, 2, 1, false><<<dim3(BS / 128, D / 128, 1), 256, 0, stream>>>(
      attn, Wot, bo, yb, D, D, D, D, 0, 0, 0, 0, 0, 0, 1, 1.f);

  // 8) x1 = x + LN(y)*g1 + be1  (fp32 + bf16 copy)
  ln_res<true><<<BS, 256, 0, stream>>>(x, yb, g1, be1, x1, x1b);

  // 9) h = mish(x1 @ W1 + b1) (bf16)
  gemm_bt<2, 2, 2, true><<<dim3(BS / 128, F / 128, 1), 256, 0, stream>>>(
      x1b, W1t, b1, hb, D, D, D, F, 0, 0, 0, 0, 0, 0, 1, 1.f);

  // 10) y2 = h @ W2 + b2 (fp32, reuse yb)
  gemm_bt<2, 2, 1, false><<<dim3(BS / 128, D / 128, 1), 256, 0, stream>>>(
      hb, W2t, b2, yb, F, F, F, D, 0, 0, 0, 0, 0, 0, 1, 1.f);

  // 11) out = x1 + LN(y2)*g2 + be2
  ln_res<false><<<BS, 256, 0, stream>>>(x1, yb, g2, be2, out, nullptr);
}

// Round 2
// 420.074 us; speedup vs baseline: 1.1840x; 1.1840x over previous
//
#include <hip/hip_runtime.h>

// ---------------------------------------------------------------------------
// EncoderLayer: x -> MHA(entmax1.5) -> +LN -> FFN(mish) -> +LN
// B=8 S=1024 D=512 H=8 hd=64 F=2048.  bf16 MFMA GEMMs, fp32 accum/epilogues.
// ---------------------------------------------------------------------------

typedef float f32x4 __attribute__((ext_vector_type(4)));
typedef __bf16 b8 __attribute__((ext_vector_type(8)));

#define DEV static __device__ __forceinline__

DEV unsigned short f2bf(float f) {
  unsigned u = __float_as_uint(f);
  u += 0x7fffu + ((u >> 16) & 1u);   // RNE
  return (unsigned short)(u >> 16);
}
DEV float bf2f(unsigned short b) { return __uint_as_float(((unsigned)b) << 16); }

DEV float mishf(float x) {
  // x * tanh(softplus(x)) == x * ((1+e^x)^2 - 1)/((1+e^x)^2 + 1)
  if (x > 20.f) return x;
  float e = __expf(x);
  float u = 1.f + e;
  u *= u;
  return x * ((u - 1.f) / (u + 1.f));
}

DEV void async16(const void* g, void* l) {
  __builtin_amdgcn_global_load_lds(
      (const __attribute__((address_space(1))) unsigned int*)g,
      (__attribute__((address_space(3))) unsigned int*)l, 16, 0, 0);
}

// ---------------------------------------------------------------------------
// Generic MFMA GEMM:  C[M,N] = alpha * A[M,K] * Bt[N,K]^T (+bias) (+mish)
// A, Bt bf16 row-major (lda/ldb leading strides). Batched via blockIdx.z with
// composite offsets off = (z/hdiv)*s1 + (z%hdiv)*s2 for A, B, C.
// Block: 256 threads = 4 waves; wave grid WM x WN, each wave does 64x64 via
// 4x4 of mfma_f32_16x16x32_bf16. BK=32 per step, global_load_lds staging,
// XOR-swizzled 16B slots so frag ds_read_b128 is 2-way-conflict (free).
// EPI: 0 none, 1 +bias, 2 +bias+mish.  OUTBF: bf16 vs fp32 output.
// ---------------------------------------------------------------------------
template <int WM, int WN, int EPI, bool OUTBF>
__global__ __launch_bounds__(256) void gemm_bt(
    const unsigned short* __restrict__ A, const unsigned short* __restrict__ Bt,
    const float* __restrict__ bias, void* __restrict__ Cp,
    int K, int lda, int ldb, int ldc,
    long sA1, long sA2, long sB1, long sB2, long sC1, long sC2,
    int hdiv, float alpha) {
  constexpr int BM = WM * 64, BN = WN * 64;
  __shared__ unsigned short smA[BM * 32];
  __shared__ unsigned short smB[BN * 32];

  const int tid = threadIdx.x;
  const int lane = tid & 63;
  const int z = blockIdx.z;
  const long zi = z / hdiv, zr = z % hdiv;
  const unsigned short* Ab = A + zi * sA1 + zr * sA2 + (long)blockIdx.x * BM * lda;
  const unsigned short* Bb = Bt + zi * sB1 + zr * sB2 + (long)blockIdx.y * BN * ldb;

  // staging descriptors: slot si holds row m=si>>2, slot s=si&3, containing
  // global k-group g = s ^ ((m>>1)&3)   (involution; breaks frag-read conflicts)
  int siA[WM];
  const unsigned short* gA[WM];
#pragma unroll
  for (int q = 0; q < WM; ++q) {
    int si = q * 256 + tid;
    int m = si >> 2, s = si & 3, g = s ^ ((m >> 1) & 3);
    siA[q] = si;
    gA[q] = Ab + (long)m * lda + g * 8;
  }
  int siB[WN];
  const unsigned short* gB[WN];
#pragma unroll
  for (int q = 0; q < WN; ++q) {
    int si = q * 256 + tid;
    int m = si >> 2, s = si & 3, g = s ^ ((m >> 1) & 3);
    siB[q] = si;
    gB[q] = Bb + (long)m * ldb + g * 8;
  }

  const int w = tid >> 6;
  const int wr = w / WN, wc = w % WN;
  const int fm = lane & 15, fg = lane >> 4;

  int aOff[4], bOff[4];
#pragma unroll
  for (int i = 0; i < 4; ++i) {
    int m = wr * 64 + i * 16 + fm;
    aOff[i] = (m * 4 + (fg ^ ((m >> 1) & 3))) * 8;
    int n = wc * 64 + i * 16 + fm;
    bOff[i] = (n * 4 + (fg ^ ((n >> 1) & 3))) * 8;
  }

  f32x4 acc[4][4];
#pragma unroll
  for (int i = 0; i < 4; ++i)
#pragma unroll
    for (int j = 0; j < 4; ++j) acc[i][j] = (f32x4){0.f, 0.f, 0.f, 0.f};

  for (int k0 = 0; k0 < K; k0 += 32) {
    __syncthreads();  // protect LDS from previous iteration's readers
#pragma unroll
    for (int q = 0; q < WM; ++q) async16(gA[q] + k0, (void*)&smA[siA[q] * 8]);
#pragma unroll
    for (int q = 0; q < WN; ++q) async16(gB[q] + k0, (void*)&smB[siB[q] * 8]);
    __syncthreads();  // implies vmcnt(0): staging complete

    b8 aF[4], bF[4];
#pragma unroll
    for (int i = 0; i < 4; ++i) aF[i] = *(const b8*)&smA[aOff[i]];
#pragma unroll
    for (int j = 0; j < 4; ++j) bF[j] = *(const b8*)&smB[bOff[j]];
#pragma unroll
    for (int i = 0; i < 4; ++i)
#pragma unroll
      for (int j = 0; j < 4; ++j)
        acc[i][j] = __builtin_amdgcn_mfma_f32_16x16x32_bf16(aF[i], bF[j], acc[i][j], 0, 0, 0);
  }

  // epilogue: C row = (lane>>4)*4 + reg, col = lane&15 (m89-verified layout)
  const long cbase = zi * sC1 + zr * sC2;
  const int row0 = blockIdx.x * BM + wr * 64 + fg * 4;
  const int col0 = blockIdx.y * BN + wc * 64 + fm;
#pragma unroll
  for (int i = 0; i < 4; ++i) {
#pragma unroll
    for (int j = 0; j < 4; ++j) {
      const int col = col0 + j * 16;
      float bv = (EPI >= 1) ? bias[col] : 0.f;
#pragma unroll
      for (int r = 0; r < 4; ++r) {
        const int row = row0 + i * 16 + r;
        float v = acc[i][j][r] * alpha + bv;
        if (EPI == 2) v = mishf(v);
        const long idx = cbase + (long)row * ldc + col;
        if constexpr (OUTBF)
          ((unsigned short*)Cp)[idx] = f2bf(v);
        else
          ((float*)Cp)[idx] = v;
      }
    }
  }
}

// ---------------------------------------------------------------------------
// fp32 -> bf16 cast (vectorized)
// ---------------------------------------------------------------------------
__global__ __launch_bounds__(256) void cast_f2b(const float* __restrict__ in,
                                                unsigned short* __restrict__ out, long n) {
  long i = ((long)blockIdx.x * 256 + threadIdx.x) * 4;
  if (i >= n) return;
  float4 v = *(const float4*)&in[i];
  unsigned lo = (unsigned)f2bf(v.x) | ((unsigned)f2bf(v.y) << 16);
  unsigned hi = (unsigned)f2bf(v.z) | ((unsigned)f2bf(v.w) << 16);
  uint2 p;
  p.x = lo;
  p.y = hi;
  *(uint2*)&out[i] = p;
}

// ---------------------------------------------------------------------------
// Transpose fp32[R,C] (ldi) -> bf16[C,R] (ldo), 32x32 LDS tiles (weights)
// ---------------------------------------------------------------------------
__global__ __launch_bounds__(256) void transpose_f2b(const float* __restrict__ in,
                                                     unsigned short* __restrict__ out,
                                                     int ldi, int ldo) {
  __shared__ float t[32][33];
  const int tx = threadIdx.x & 31, ty = threadIdx.x >> 5;
  const int r0 = blockIdx.y * 32, c0 = blockIdx.x * 32;
#pragma unroll
  for (int q = 0; q < 4; ++q) {
    int r = ty + q * 8;
    t[r][tx] = in[(long)(r0 + r) * ldi + c0 + tx];
  }
  __syncthreads();
#pragma unroll
  for (int q = 0; q < 4; ++q) {
    int r = ty + q * 8;
    out[(long)(c0 + r) * ldo + r0 + tx] = f2bf(t[tx][r]);
  }
}

// bf16 batched transpose (for V -> V^T per (b,h))
__global__ __launch_bounds__(256) void transpose_b2b(const unsigned short* __restrict__ in,
                                                     unsigned short* __restrict__ out,
                                                     int ldi, int ldo, long i1, long i2,
                                                     long o1, long o2, int hdiv) {
  __shared__ unsigned short t[32][33];
  const int z = blockIdx.z;
  in += (long)(z / hdiv) * i1 + (long)(z % hdiv) * i2;
  out += (long)(z / hdiv) * o1 + (long)(z % hdiv) * o2;
  const int tx = threadIdx.x & 31, ty = threadIdx.x >> 5;
  const int r0 = blockIdx.y * 32, c0 = blockIdx.x * 32;
#pragma unroll
  for (int q = 0; q < 4; ++q) {
    int r = ty + q * 8;
    t[r][tx] = in[(long)(r0 + r) * ldi + c0 + tx];
  }
  __syncthreads();
#pragma unroll
  for (int q = 0; q < 4; ++q) {
    int r = ty + q * 8;
    out[(long)(c0 + r) * ldo + r0 + tx] = t[tx][r];
  }
}

// ---------------------------------------------------------------------------
// entmax 1.5 over rows of 1024 (in-place on bf16 buffer). One wave per row.
// z already = scores/2 (folded into GEMM alpha). tau* solves sum (z-tau)_+^2=1.
// Register-resident Newton from tau0 = max-1 (monotone from below: f convex
// decreasing, so tangent roots stay below tau*). All 16 elems/lane stay in
// VGPRs; clamp-at-0 makes dead elements free — no compaction, no LDS, no
// atomics. Break at s2-1 < 1e-4 (tau error < 5e-5, invisible in bf16 out).
// ---------------------------------------------------------------------------
__global__ __launch_bounds__(256) void entmax_rows(unsigned short* __restrict__ P) {
  const int tid = threadIdx.x, lane = tid & 63, wv = tid >> 6;
  const long row = (long)blockIdx.x * 4 + wv;
  unsigned short* p = P + row * 1024;

  float zv[16];
  union {
    uint4 v;
    unsigned short u[8];
  } a, b;
  a.v = *(const uint4*)(p + lane * 16);
  b.v = *(const uint4*)(p + lane * 16 + 8);
#pragma unroll
  for (int i = 0; i < 8; ++i) {
    zv[i] = bf2f(a.u[i]);
    zv[8 + i] = bf2f(b.u[i]);
  }

  float m = zv[0];
#pragma unroll
  for (int i = 1; i < 16; ++i) m = fmaxf(m, zv[i]);
#pragma unroll
  for (int o = 32; o; o >>= 1) m = fmaxf(m, __shfl_xor(m, o));

#pragma unroll
  for (int i = 0; i < 16; ++i) zv[i] -= m;

  float tau = -1.f;
  for (int it = 0; it < 16; ++it) {
    float s1 = 0.f, s2 = 0.f;
#pragma unroll
    for (int i = 0; i < 16; ++i) {
      float h = fmaxf(zv[i] - tau, 0.f);
      s1 += h;
      s2 = fmaf(h, h, s2);
    }
#pragma unroll
    for (int o = 32; o; o >>= 1) {
      s1 += __shfl_xor(s1, o);
      s2 += __shfl_xor(s2, o);
    }
    float ex = s2 - 1.f;
    if (ex < 1e-4f) break;  // wave-uniform (post-reduction values identical)
    tau += ex / (2.f * s1);
  }

#pragma unroll
  for (int i = 0; i < 8; ++i) {
    float h0 = fmaxf(zv[i] - tau, 0.f);
    float h1 = fmaxf(zv[8 + i] - tau, 0.f);
    a.u[i] = f2bf(h0 * h0);
    b.u[i] = f2bf(h1 * h1);
  }
  *(uint4*)(p + lane * 16) = a.v;
  *(uint4*)(p + lane * 16 + 8) = b.v;
}

// ---------------------------------------------------------------------------
// out = xin + LayerNorm(y)*g + be   (row length 512, 256 threads/row)
// optionally also writes bf16 copy of out.
// ---------------------------------------------------------------------------
template <bool WB>
__global__ __launch_bounds__(256) void ln_res(const float* __restrict__ xin,
                                              const float* __restrict__ y,
                                              const float* __restrict__ g,
                                              const float* __restrict__ be,
                                              float* __restrict__ xo,
                                              unsigned short* __restrict__ xob) {
  const int row = blockIdx.x, tid = threadIdx.x, lane = tid & 63, wv = tid >> 6;
  const long base = (long)row * 512 + tid * 2;
  float2 v = *(const float2*)&y[base];
  float s1 = v.x + v.y, s2 = v.x * v.x + v.y * v.y;
  for (int o = 32; o; o >>= 1) {
    s1 += __shfl_xor(s1, o);
    s2 += __shfl_xor(s2, o);
  }
  __shared__ float red[4][2];
  if (lane == 0) {
    red[wv][0] = s1;
    red[wv][1] = s2;
  }
  __syncthreads();
  s1 = red[0][0] + red[1][0] + red[2][0] + red[3][0];
  s2 = red[0][1] + red[1][1] + red[2][1] + red[3][1];
  const float mu = s1 * (1.f / 512.f);
  const float rstd = rsqrtf(s2 * (1.f / 512.f) - mu * mu + 1e-5f);
  const int c = tid * 2;
  float2 xv = *(const float2*)&xin[base];
  float o0 = xv.x + (v.x - mu) * rstd * g[c] + be[c];
  float o1 = xv.y + (v.y - mu) * rstd * g[c + 1] + be[c + 1];
  float2 ov;
  ov.x = o0;
  ov.y = o1;
  *(float2*)&xo[base] = ov;
  if constexpr (WB) {
    unsigned pk = (unsigned)f2bf(o0) | ((unsigned)f2bf(o1) << 16);
    *(unsigned*)&xob[base] = pk;
  }
}

// ---------------------------------------------------------------------------
extern "C" void kernel_launch(void* const* d_in, const int* in_sizes, int n_in,
                              void* d_out, int out_size, void* d_ws, size_t ws_size,
                              hipStream_t stream) {
  const int B = 8, S = 1024, D = 512, H = 8, F = 2048;
  const int BS = B * S;  // 8192 rows

  const float* x = (const float*)d_in[0];
  const float* Wq = (const float*)d_in[1];
  const float* bq = (const float*)d_in[2];
  const float* Wk = (const float*)d_in[3];
  const float* bk = (const float*)d_in[4];
  const float* Wv = (const float*)d_in[5];
  const float* bv = (const float*)d_in[6];
  const float* Wo = (const float*)d_in[7];
  const float* bo = (const float*)d_in[8];
  const float* g1 = (const float*)d_in[9];
  const float* be1 = (const float*)d_in[10];
  const float* W1 = (const float*)d_in[11];
  const float* b1 = (const float*)d_in[12];
  const float* W2 = (const float*)d_in[13];
  const float* b2 = (const float*)d_in[14];
  const float* g2 = (const float*)d_in[15];
  const float* be2 = (const float*)d_in[16];
  float* out = (float*)d_out;

  char* w = (char*)d_ws;
  size_t off = 0;
  auto alloc = [&](size_t bytes) -> void* {
    void* p = w + off;
    off += bytes;
    off = (off + 255) & ~(size_t)255;
    return p;
  };

  unsigned short* xb = (unsigned short*)alloc((size_t)BS * D * 2);
  unsigned short* Wqt = (unsigned short*)alloc((size_t)D * D * 2);
  unsigned short* Wkt = (unsigned short*)alloc((size_t)D * D * 2);
  unsigned short* Wvt = (unsigned short*)alloc((size_t)D * D * 2);
  unsigned short* Wot = (unsigned short*)alloc((size_t)D * D * 2);
  unsigned short* W1t = (unsigned short*)alloc((size_t)F * D * 2);
  unsigned short* W2t = (unsigned short*)alloc((size_t)D * F * 2);
  unsigned short* Qb = (unsigned short*)alloc((size_t)BS * D * 2);
  unsigned short* Kb = (unsigned short*)alloc((size_t)BS * D * 2);
  unsigned short* Vb = (unsigned short*)alloc((size_t)BS * D * 2);
  unsigned short* Vt = (unsigned short*)alloc((size_t)BS * D * 2);
  unsigned short* P = (unsigned short*)alloc((size_t)B * H * S * S * 2);  // 128 MiB
  float* yb = (float*)alloc((size_t)BS * D * 4);
  float* x1 = (float*)alloc((size_t)BS * D * 4);
  unsigned short* hb = (unsigned short*)alloc((size_t)BS * F * 2);
  unsigned short* attn = Qb;  // reuse (Qb dead after scores GEMM)
  unsigned short* x1b = xb;   // reuse (xb dead after QKV GEMMs)

  const long SD = (long)S * D;      // 524288
  const long SS = (long)S * S;      // 1048576
  const long HSS = (long)H * SS;    // per-b score stride
  const long HDS = (long)H * 64 * S;  // per-b Vt stride

  // 1) casts + weight transposes (bf16, N x K form)
  cast_f2b<<<(BS * D) / 1024, 256, 0, stream>>>(x, xb, (long)BS * D);
  transpose_f2b<<<dim3(16, 16, 1), 256, 0, stream>>>(Wq, Wqt, D, D);
  transpose_f2b<<<dim3(16, 16, 1), 256, 0, stream>>>(Wk, Wkt, D, D);
  transpose_f2b<<<dim3(16, 16, 1), 256, 0, stream>>>(Wv, Wvt, D, D);
  transpose_f2b<<<dim3(16, 16, 1), 256, 0, stream>>>(Wo, Wot, D, D);
  transpose_f2b<<<dim3(F / 32, D / 32, 1), 256, 0, stream>>>(W1, W1t, F, D);
  transpose_f2b<<<dim3(D / 32, F / 32, 1), 256, 0, stream>>>(W2, W2t, D, F);

  // 2) Q,K,V projections (bf16 out)
  gemm_bt<2, 2, 1, true><<<dim3(BS / 128, D / 128, 1), 256, 0, stream>>>(
      xb, Wqt, bq, Qb, D, D, D, D, 0, 0, 0, 0, 0, 0, 1, 1.f);
  gemm_bt<2, 2, 1, true><<<dim3(BS / 128, D / 128, 1), 256, 0, stream>>>(
      xb, Wkt, bk, Kb, D, D, D, D, 0, 0, 0, 0, 0, 0, 1, 1.f);
  gemm_bt<2, 2, 1, true><<<dim3(BS / 128, D / 128, 1), 256, 0, stream>>>(
      xb, Wvt, bv, Vb, D, D, D, D, 0, 0, 0, 0, 0, 0, 1, 1.f);

  // 3) V -> Vt[(b,h), d, s]
  transpose_b2b<<<dim3(2, 32, B * H), 256, 0, stream>>>(Vb, Vt, D, S, SD, 64, HDS,
                                                        (long)64 * S, H);

  // 4) scores z = Q K^T / 16  (the /8 attention scale * entmax /2), bf16
  gemm_bt<2, 2, 0, true><<<dim3(S / 128, S / 128, B * H), 256, 0, stream>>>(
      Qb, Kb, nullptr, P, 64, D, D, S, SD, 64, SD, 64, HSS, SS, H, 1.f / 16.f);

  // 5) entmax-1.5 per row, in place
  entmax_rows<<<(B * H * S) / 4, 256, 0, stream>>>(P);

  // 6) attn_out = P @ V   (256x64 tiles)
  gemm_bt<4, 1, 0, true><<<dim3(S / 256, 1, B * H), 256, 0, stream>>>(
      P, Vt, nullptr, attn, S, S, S, D, HSS, SS, HDS, (long)64 * S, SD, 64, H, 1.f);

  // 7) y = attn_out @ Wo + bo (fp32)
  gemm_bt<2, 2, 1, false><<<dim3(BS / 128, D / 128, 1), 256, 0, stream>>>(
      attn, Wot, bo, yb, D, D, D, D, 0, 0, 0, 0, 0, 0, 1, 1.f);

  // 8) x1 = x + LN(y)*g1 + be1  (fp32 + bf16 copy)
  ln_res<true><<<BS, 256, 0, stream>>>(x, yb, g1, be1, x1, x1b);

  // 9) h = mish(x1 @ W1 + b1) (bf16)
  gemm_bt<2, 2, 2, true><<<dim3(BS / 128, F / 128, 1), 256, 0, stream>>>(
      x1b, W1t, b1, hb, D, D, D, F, 0, 0, 0, 0, 0, 0, 1, 1.f);

  // 10) y2 = h @ W2 + b2 (fp32, reuse yb)
  gemm_bt<2, 2, 1, false><<<dim3(BS / 128, D / 128, 1), 256, 0, stream>>>(
      hb, W2t, b2, yb, F, F, F, D, 0, 0, 0, 0, 0, 0, 1, 1.f);

  // 11) out = x1 + LN(y2)*g2 + be2
  ln_res<false><<<BS, 256, 0, stream>>>(x1, yb, g2, be2, out, nullptr);
}